// Round 1
// baseline (5705.943 us; speedup 1.0000x reference)
//
#include <hip/hip_runtime.h>

#define NN 100000
#define NE 1600000
#define D_IN 128
#define D_HID 128
#define D_OUT 64

// ---------------------------------------------------------------------------
// degree: deg[dst] += 1 per edge
__global__ void deg_kernel(const int* __restrict__ dst, float* __restrict__ deg, int E) {
    int e = blockIdx.x * blockDim.x + threadIdx.x;
    if (e < E) atomicAdd(&deg[dst[e]], 1.0f);
}

// inv = 1/(deg+1)
__global__ void inv_kernel(const float* __restrict__ deg, float* __restrict__ inv, int N) {
    int n = blockIdx.x * blockDim.x + threadIdx.x;
    if (n < N) inv[n] = 1.0f / (deg[n] + 1.0f);
}

// ---------------------------------------------------------------------------
// scatter-add: agg[dst] += h[src], 128 features/edge, 32 threads/edge (4 floats each)
__global__ void scatter_kernel(const float* __restrict__ h, const int* __restrict__ src,
                               const int* __restrict__ dst, float* __restrict__ agg, int E) {
    long long tid = (long long)blockIdx.x * blockDim.x + threadIdx.x;
    int e = (int)(tid >> 5);
    if (e >= E) return;
    int f = ((int)tid & 31) * 4;
    int s = src[e];
    int d = dst[e];
    const float4 v = *reinterpret_cast<const float4*>(h + (size_t)s * 128 + f);
    float* a = agg + (size_t)d * 128 + f;
    atomicAdd(a + 0, v.x);
    atomicAdd(a + 1, v.y);
    atomicAdd(a + 2, v.z);
    atomicAdd(a + 3, v.w);
}

// ---------------------------------------------------------------------------
// layer 1 dense: h1[n][j] = relu( sum_k (agg[n][k]+x[n][k])*inv[n] * W1[k][j] + b1[j] )
// block = 128 threads (j), 4 nodes per block
__global__ void dense1_kernel(const float* __restrict__ agg, const float* __restrict__ x,
                              const float* __restrict__ inv, const float* __restrict__ W1,
                              const float* __restrict__ b1, float* __restrict__ h1, int N) {
    __shared__ float hn[4][128];
    const int tid = threadIdx.x;           // output column j
    const int nodeBase = blockIdx.x * 4;

    #pragma unroll
    for (int m = 0; m < 4; ++m) {
        int n = nodeBase + m;
        if (n < N) {
            hn[m][tid] = (agg[(size_t)n * 128 + tid] + x[(size_t)n * 128 + tid]) * inv[n];
        }
    }
    __syncthreads();

    float acc0 = b1[tid], acc1 = acc0, acc2 = acc0, acc3 = acc0;
    #pragma unroll 8
    for (int k = 0; k < 128; ++k) {
        float w = W1[k * 128 + tid];
        acc0 = fmaf(hn[0][k], w, acc0);
        acc1 = fmaf(hn[1][k], w, acc1);
        acc2 = fmaf(hn[2][k], w, acc2);
        acc3 = fmaf(hn[3][k], w, acc3);
    }

    if (nodeBase + 0 < N) h1[(size_t)(nodeBase + 0) * 128 + tid] = fmaxf(acc0, 0.0f);
    if (nodeBase + 1 < N) h1[(size_t)(nodeBase + 1) * 128 + tid] = fmaxf(acc1, 0.0f);
    if (nodeBase + 2 < N) h1[(size_t)(nodeBase + 2) * 128 + tid] = fmaxf(acc2, 0.0f);
    if (nodeBase + 3 < N) h1[(size_t)(nodeBase + 3) * 128 + tid] = fmaxf(acc3, 0.0f);
}

// ---------------------------------------------------------------------------
// layer 2 dense: out[n][j] = sum_k (agg[n][k]+h1[n][k])*inv[n] * W2[k][j] + b2[j]
// block = 64 threads (j), 8 nodes per block
__global__ void dense2_kernel(const float* __restrict__ agg, const float* __restrict__ h1,
                              const float* __restrict__ inv, const float* __restrict__ W2,
                              const float* __restrict__ b2, float* __restrict__ out, int N) {
    __shared__ float hn[8][128];
    const int tid = threadIdx.x;           // output column j (0..63)
    const int nodeBase = blockIdx.x * 8;

    #pragma unroll
    for (int m = 0; m < 8; ++m) {
        int n = nodeBase + m;
        if (n < N) {
            float iv = inv[n];
            #pragma unroll
            for (int p = 0; p < 2; ++p) {
                int k = p * 64 + tid;
                hn[m][k] = (agg[(size_t)n * 128 + k] + h1[(size_t)n * 128 + k]) * iv;
            }
        }
    }
    __syncthreads();

    float acc[8];
    float bb = b2[tid];
    #pragma unroll
    for (int m = 0; m < 8; ++m) acc[m] = bb;

    #pragma unroll 8
    for (int k = 0; k < 128; ++k) {
        float w = W2[k * 64 + tid];
        #pragma unroll
        for (int m = 0; m < 8; ++m) acc[m] = fmaf(hn[m][k], w, acc[m]);
    }

    #pragma unroll
    for (int m = 0; m < 8; ++m) {
        int n = nodeBase + m;
        if (n < N) out[(size_t)n * 64 + tid] = acc[m];
    }
}

// ---------------------------------------------------------------------------
extern "C" void kernel_launch(void* const* d_in, const int* in_sizes, int n_in,
                              void* d_out, int out_size, void* d_ws, size_t ws_size,
                              hipStream_t stream) {
    const float* x   = (const float*)d_in[0];   // [N,128]
    const float* W1  = (const float*)d_in[1];   // [128,128]
    const float* b1  = (const float*)d_in[2];   // [128]
    const float* W2  = (const float*)d_in[3];   // [128,64]
    const float* b2  = (const float*)d_in[4];   // [64]
    const int* esrc  = (const int*)d_in[5];     // [E]
    const int* edst  = (const int*)d_in[6];     // [E]
    float* out = (float*)d_out;                 // [N,64]

    float* ws  = (float*)d_ws;
    float* deg = ws;                                    // N
    float* inv = deg + NN;                              // N
    float* agg = inv + NN;                              // N*128
    float* h1  = agg + (size_t)NN * 128;                // N*128

    // zero deg + agg
    hipMemsetAsync(deg, 0, NN * sizeof(float), stream);
    hipMemsetAsync(agg, 0, (size_t)NN * 128 * sizeof(float), stream);

    deg_kernel<<<(NE + 255) / 256, 256, 0, stream>>>(edst, deg, NE);
    inv_kernel<<<(NN + 255) / 256, 256, 0, stream>>>(deg, inv, NN);

    // layer 1
    {
        long long total = (long long)NE * 32;
        int blocks = (int)((total + 255) / 256);
        scatter_kernel<<<blocks, 256, 0, stream>>>(x, esrc, edst, agg, NE);
    }
    dense1_kernel<<<NN / 4, 128, 0, stream>>>(agg, x, inv, W1, b1, h1, NN);

    // layer 2
    hipMemsetAsync(agg, 0, (size_t)NN * 128 * sizeof(float), stream);
    {
        long long total = (long long)NE * 32;
        int blocks = (int)((total + 255) / 256);
        scatter_kernel<<<blocks, 256, 0, stream>>>(h1, esrc, edst, agg, NE);
    }
    dense2_kernel<<<NN / 8, 64, 0, stream>>>(agg, h1, inv, W2, b2, out, NN);
}

// Round 2
// 704.040 us; speedup vs baseline: 8.1046x; 8.1046x over previous
//
#include <hip/hip_runtime.h>

#define NN 100000
#define NE 1600000
#define NB ((NN + 255) / 256)   // 391 scan blocks

// ---------------------------------------------------------------------------
// CSR build: count in-degree (int atomics)
__global__ void count_kernel(const int* __restrict__ dst, int* __restrict__ cnt, int E) {
    int e = blockIdx.x * blockDim.x + threadIdx.x;
    if (e < E) atomicAdd(&cnt[dst[e]], 1);
}

// per-256-block sums of cnt
__global__ void blocksum_kernel(const int* __restrict__ cnt, int* __restrict__ bsum, int N) {
    __shared__ int s[256];
    int i = blockIdx.x * 256 + threadIdx.x;
    s[threadIdx.x] = (i < N) ? cnt[i] : 0;
    __syncthreads();
    for (int o = 128; o > 0; o >>= 1) {
        if (threadIdx.x < o) s[threadIdx.x] += s[threadIdx.x + o];
        __syncthreads();
    }
    if (threadIdx.x == 0) bsum[blockIdx.x] = s[0];
}

// single-block exclusive scan of the block sums (NB <= 512)
__global__ void scanb_kernel(int* __restrict__ bsum, int nb) {
    __shared__ int s[512];
    int t = threadIdx.x;
    s[t] = (t < nb) ? bsum[t] : 0;
    __syncthreads();
    for (int o = 1; o < 512; o <<= 1) {
        int v = (t >= o) ? s[t - o] : 0;
        __syncthreads();
        if (t >= o) s[t] += v;
        __syncthreads();
    }
    if (t < nb) bsum[t] = (t == 0) ? 0 : s[t - 1];   // exclusive
}

// per-block exclusive scan + block offset -> rowptr
__global__ void rowptr_kernel(const int* __restrict__ cnt, const int* __restrict__ boff,
                              int* __restrict__ rowptr, int N) {
    __shared__ int s[256];
    int t = threadIdx.x;
    int i = blockIdx.x * 256 + t;
    int v = (i < N) ? cnt[i] : 0;
    s[t] = v;
    __syncthreads();
    for (int o = 1; o < 256; o <<= 1) {
        int u = (t >= o) ? s[t - o] : 0;
        __syncthreads();
        if (t >= o) s[t] += u;
        __syncthreads();
    }
    if (i < N) rowptr[i] = boff[blockIdx.x] + s[t] - v;   // exclusive
    if (i == N - 1) rowptr[N] = boff[blockIdx.x] + s[t];  // total = E
}

// cursor[n] = rowptr[n]; inv[n] = 1/(deg+1)
__global__ void cursor_inv_kernel(const int* __restrict__ rowptr, int* __restrict__ cursor,
                                  float* __restrict__ inv, int N) {
    int n = blockIdx.x * blockDim.x + threadIdx.x;
    if (n < N) {
        int r0 = rowptr[n], r1 = rowptr[n + 1];
        cursor[n] = r0;
        inv[n] = 1.0f / (float)(r1 - r0 + 1);
    }
}

// place src ids grouped by dst
__global__ void fill_kernel(const int* __restrict__ src, const int* __restrict__ dst,
                            int* __restrict__ cursor, int* __restrict__ col, int E) {
    int e = blockIdx.x * blockDim.x + threadIdx.x;
    if (e < E) {
        int pos = atomicAdd(&cursor[dst[e]], 1);
        col[pos] = src[e];
    }
}

// ---------------------------------------------------------------------------
// gather aggregation: one wave (64 lanes) per node, 2 floats per lane.
// agg[n] = sum over in-edges of h[src]
__global__ void agg_kernel(const float* __restrict__ h, const int* __restrict__ rowptr,
                           const int* __restrict__ col, float* __restrict__ agg, int N) {
    int wave = (blockIdx.x * blockDim.x + threadIdx.x) >> 6;
    if (wave >= N) return;
    int lane = threadIdx.x & 63;
    int start = rowptr[wave], end = rowptr[wave + 1];

    float2 acc0 = {0.0f, 0.0f}, acc1 = {0.0f, 0.0f};
    int e = start;
    for (; e + 1 < end; e += 2) {
        int s0 = col[e], s1 = col[e + 1];
        float2 v0 = *reinterpret_cast<const float2*>(h + (size_t)s0 * 128 + lane * 2);
        float2 v1 = *reinterpret_cast<const float2*>(h + (size_t)s1 * 128 + lane * 2);
        acc0.x += v0.x; acc0.y += v0.y;
        acc1.x += v1.x; acc1.y += v1.y;
    }
    if (e < end) {
        int s0 = col[e];
        float2 v0 = *reinterpret_cast<const float2*>(h + (size_t)s0 * 128 + lane * 2);
        acc0.x += v0.x; acc0.y += v0.y;
    }
    float2 r = {acc0.x + acc1.x, acc0.y + acc1.y};
    *reinterpret_cast<float2*>(agg + (size_t)wave * 128 + lane * 2) = r;
}

// ---------------------------------------------------------------------------
// layer 1 dense: h1[n][j] = relu( sum_k (agg[n][k]+x[n][k])*inv[n] * W1[k][j] + b1[j] )
__global__ void dense1_kernel(const float* __restrict__ agg, const float* __restrict__ x,
                              const float* __restrict__ inv, const float* __restrict__ W1,
                              const float* __restrict__ b1, float* __restrict__ h1, int N) {
    __shared__ float hn[4][128];
    const int tid = threadIdx.x;
    const int nodeBase = blockIdx.x * 4;

    #pragma unroll
    for (int m = 0; m < 4; ++m) {
        int n = nodeBase + m;
        if (n < N) {
            hn[m][tid] = (agg[(size_t)n * 128 + tid] + x[(size_t)n * 128 + tid]) * inv[n];
        }
    }
    __syncthreads();

    float acc0 = b1[tid], acc1 = acc0, acc2 = acc0, acc3 = acc0;
    #pragma unroll 8
    for (int k = 0; k < 128; ++k) {
        float w = W1[k * 128 + tid];
        acc0 = fmaf(hn[0][k], w, acc0);
        acc1 = fmaf(hn[1][k], w, acc1);
        acc2 = fmaf(hn[2][k], w, acc2);
        acc3 = fmaf(hn[3][k], w, acc3);
    }

    if (nodeBase + 0 < N) h1[(size_t)(nodeBase + 0) * 128 + tid] = fmaxf(acc0, 0.0f);
    if (nodeBase + 1 < N) h1[(size_t)(nodeBase + 1) * 128 + tid] = fmaxf(acc1, 0.0f);
    if (nodeBase + 2 < N) h1[(size_t)(nodeBase + 2) * 128 + tid] = fmaxf(acc2, 0.0f);
    if (nodeBase + 3 < N) h1[(size_t)(nodeBase + 3) * 128 + tid] = fmaxf(acc3, 0.0f);
}

// layer 2 dense: out[n][j] = sum_k (agg[n][k]+h1[n][k])*inv[n] * W2[k][j] + b2[j]
__global__ void dense2_kernel(const float* __restrict__ agg, const float* __restrict__ h1,
                              const float* __restrict__ inv, const float* __restrict__ W2,
                              const float* __restrict__ b2, float* __restrict__ out, int N) {
    __shared__ float hn[8][128];
    const int tid = threadIdx.x;          // 0..63
    const int nodeBase = blockIdx.x * 8;

    #pragma unroll
    for (int m = 0; m < 8; ++m) {
        int n = nodeBase + m;
        if (n < N) {
            float iv = inv[n];
            #pragma unroll
            for (int p = 0; p < 2; ++p) {
                int k = p * 64 + tid;
                hn[m][k] = (agg[(size_t)n * 128 + k] + h1[(size_t)n * 128 + k]) * iv;
            }
        }
    }
    __syncthreads();

    float acc[8];
    float bb = b2[tid];
    #pragma unroll
    for (int m = 0; m < 8; ++m) acc[m] = bb;

    #pragma unroll 8
    for (int k = 0; k < 128; ++k) {
        float w = W2[k * 64 + tid];
        #pragma unroll
        for (int m = 0; m < 8; ++m) acc[m] = fmaf(hn[m][k], w, acc[m]);
    }

    #pragma unroll
    for (int m = 0; m < 8; ++m) {
        int n = nodeBase + m;
        if (n < N) out[(size_t)n * 64 + tid] = acc[m];
    }
}

// ---------------------------------------------------------------------------
extern "C" void kernel_launch(void* const* d_in, const int* in_sizes, int n_in,
                              void* d_out, int out_size, void* d_ws, size_t ws_size,
                              hipStream_t stream) {
    const float* x   = (const float*)d_in[0];   // [N,128]
    const float* W1  = (const float*)d_in[1];   // [128,128]
    const float* b1  = (const float*)d_in[2];   // [128]
    const float* W2  = (const float*)d_in[3];   // [128,64]
    const float* b2  = (const float*)d_in[4];   // [64]
    const int* esrc  = (const int*)d_in[5];     // [E]
    const int* edst  = (const int*)d_in[6];     // [E]
    float* out = (float*)d_out;                 // [N,64]

    // workspace layout
    int*   rowptr = (int*)d_ws;                         // N+1
    int*   cnt    = rowptr + NN + 1;                    // N (reused as cursor)
    int*   col    = cnt + NN;                           // E
    int*   bsum   = col + NE;                           // 512
    float* inv    = (float*)(bsum + 512);               // N
    float* agg    = inv + NN;                           // N*128
    float* h1     = agg + (size_t)NN * 128;             // N*128

    // ---- CSR build (graph is the same for both layers) ----
    hipMemsetAsync(cnt, 0, NN * sizeof(int), stream);
    count_kernel<<<(NE + 255) / 256, 256, 0, stream>>>(edst, cnt, NE);
    blocksum_kernel<<<NB, 256, 0, stream>>>(cnt, bsum, NN);
    scanb_kernel<<<1, 512, 0, stream>>>(bsum, NB);
    rowptr_kernel<<<NB, 256, 0, stream>>>(cnt, bsum, rowptr, NN);
    cursor_inv_kernel<<<(NN + 255) / 256, 256, 0, stream>>>(rowptr, cnt, inv, NN);
    fill_kernel<<<(NE + 255) / 256, 256, 0, stream>>>(esrc, edst, cnt, col, NE);

    // ---- layer 1 ----
    agg_kernel<<<(NN + 3) / 4, 256, 0, stream>>>(x, rowptr, col, agg, NN);
    dense1_kernel<<<NN / 4, 128, 0, stream>>>(agg, x, inv, W1, b1, h1, NN);

    // ---- layer 2 ----
    agg_kernel<<<(NN + 3) / 4, 256, 0, stream>>>(h1, rowptr, col, agg, NN);
    dense2_kernel<<<NN / 8, 64, 0, stream>>>(agg, h1, inv, W2, b2, out, NN);
}

// Round 3
// 665.617 us; speedup vs baseline: 8.5724x; 1.0577x over previous
//
#include <hip/hip_runtime.h>

#define NN 100000
#define NE 1600000
#define NB ((NN + 255) / 256)   // 391 scan blocks

// ---------------------------------------------------------------------------
// CSR build: count in-degree (int atomics)
__global__ void count_kernel(const int* __restrict__ dst, int* __restrict__ cnt, int E) {
    int e = blockIdx.x * blockDim.x + threadIdx.x;
    if (e < E) atomicAdd(&cnt[dst[e]], 1);
}

__global__ void blocksum_kernel(const int* __restrict__ cnt, int* __restrict__ bsum, int N) {
    __shared__ int s[256];
    int i = blockIdx.x * 256 + threadIdx.x;
    s[threadIdx.x] = (i < N) ? cnt[i] : 0;
    __syncthreads();
    for (int o = 128; o > 0; o >>= 1) {
        if (threadIdx.x < o) s[threadIdx.x] += s[threadIdx.x + o];
        __syncthreads();
    }
    if (threadIdx.x == 0) bsum[blockIdx.x] = s[0];
}

__global__ void scanb_kernel(int* __restrict__ bsum, int nb) {
    __shared__ int s[512];
    int t = threadIdx.x;
    s[t] = (t < nb) ? bsum[t] : 0;
    __syncthreads();
    for (int o = 1; o < 512; o <<= 1) {
        int v = (t >= o) ? s[t - o] : 0;
        __syncthreads();
        if (t >= o) s[t] += v;
        __syncthreads();
    }
    if (t < nb) bsum[t] = (t == 0) ? 0 : s[t - 1];   // exclusive
}

__global__ void rowptr_kernel(const int* __restrict__ cnt, const int* __restrict__ boff,
                              int* __restrict__ rowptr, int N) {
    __shared__ int s[256];
    int t = threadIdx.x;
    int i = blockIdx.x * 256 + t;
    int v = (i < N) ? cnt[i] : 0;
    s[t] = v;
    __syncthreads();
    for (int o = 1; o < 256; o <<= 1) {
        int u = (t >= o) ? s[t - o] : 0;
        __syncthreads();
        if (t >= o) s[t] += u;
        __syncthreads();
    }
    if (i < N) rowptr[i] = boff[blockIdx.x] + s[t] - v;
    if (i == N - 1) rowptr[N] = boff[blockIdx.x] + s[t];
}

__global__ void cursor_inv_kernel(const int* __restrict__ rowptr, int* __restrict__ cursor,
                                  float* __restrict__ inv, int N) {
    int n = blockIdx.x * blockDim.x + threadIdx.x;
    if (n < N) {
        int r0 = rowptr[n], r1 = rowptr[n + 1];
        cursor[n] = r0;
        inv[n] = 1.0f / (float)(r1 - r0 + 1);
    }
}

__global__ void fill_kernel(const int* __restrict__ src, const int* __restrict__ dst,
                            int* __restrict__ cursor, int* __restrict__ col, int E) {
    int e = blockIdx.x * blockDim.x + threadIdx.x;
    if (e < E) {
        int pos = atomicAdd(&cursor[dst[e]], 1);
        col[pos] = src[e];
    }
}

// ---------------------------------------------------------------------------
// GEMM1: y = x @ W1   [N,128] x [128,128], 8 nodes/block, 128 threads
__global__ void gemm1_kernel(const float* __restrict__ x, const float* __restrict__ W1,
                             float* __restrict__ y, int N) {
    __shared__ float xs[8][128];
    const int j = threadIdx.x;
    const int nb = blockIdx.x * 8;

    #pragma unroll
    for (int m = 0; m < 8; ++m) {
        int n = nb + m;
        if (n < N) xs[m][j] = x[(size_t)n * 128 + j];
    }
    __syncthreads();

    float acc[8];
    #pragma unroll
    for (int m = 0; m < 8; ++m) acc[m] = 0.0f;

    #pragma unroll 8
    for (int k = 0; k < 128; k += 2) {
        float w0 = W1[k * 128 + j];
        float w1 = W1[(k + 1) * 128 + j];
        #pragma unroll
        for (int m = 0; m < 8; ++m) {
            float2 v = *reinterpret_cast<const float2*>(&xs[m][k]);
            acc[m] = fmaf(v.x, w0, acc[m]);
            acc[m] = fmaf(v.y, w1, acc[m]);
        }
    }

    #pragma unroll
    for (int m = 0; m < 8; ++m) {
        int n = nb + m;
        if (n < N) y[(size_t)n * 128 + j] = acc[m];
    }
}

// GEMM2: z = h1 @ W2   [N,128] x [128,64], 32 nodes/block, 256 threads
__global__ void gemm2_kernel(const float* __restrict__ h1, const float* __restrict__ W2,
                             float* __restrict__ z, int N) {
    __shared__ float hs[32 * 128];
    const int t = threadIdx.x;
    const int j = t & 63;
    const int grp = t >> 6;          // 0..3, 8 nodes each
    const int nb = blockIdx.x * 32;

    const int lim = (N - nb) * 128;  // elements available
    for (int i = t; i < 32 * 128; i += 256) {
        hs[i] = (i < lim) ? h1[(size_t)nb * 128 + i] : 0.0f;
    }
    __syncthreads();

    float acc[8];
    #pragma unroll
    for (int m = 0; m < 8; ++m) acc[m] = 0.0f;

    #pragma unroll 8
    for (int k = 0; k < 128; k += 2) {
        float w0 = W2[k * 64 + j];
        float w1 = W2[(k + 1) * 64 + j];
        #pragma unroll
        for (int m = 0; m < 8; ++m) {
            float2 v = *reinterpret_cast<const float2*>(&hs[(grp * 8 + m) * 128 + k]);
            acc[m] = fmaf(v.x, w0, acc[m]);
            acc[m] = fmaf(v.y, w1, acc[m]);
        }
    }

    #pragma unroll
    for (int m = 0; m < 8; ++m) {
        int n = nb + grp * 8 + m;
        if (n < N) z[(size_t)n * 64 + j] = acc[m];
    }
}

// ---------------------------------------------------------------------------
// agg1: h1[n] = relu((sum_src y[src] + y[n]) * inv[n] + b1), wave/node, float2/lane
__global__ void agg1_kernel(const float* __restrict__ y, const int* __restrict__ rowptr,
                            const int* __restrict__ col, const float* __restrict__ inv,
                            const float* __restrict__ b1, float* __restrict__ h1, int N) {
    int wave = (blockIdx.x * blockDim.x + threadIdx.x) >> 6;
    if (wave >= N) return;
    int lane = threadIdx.x & 63;
    int start = rowptr[wave], end = rowptr[wave + 1];

    float2 a0 = {0, 0}, a1 = {0, 0}, a2 = {0, 0}, a3 = {0, 0};
    int e = start;
    for (; e + 3 < end; e += 4) {
        int s0 = __builtin_amdgcn_readfirstlane(col[e]);
        int s1 = __builtin_amdgcn_readfirstlane(col[e + 1]);
        int s2 = __builtin_amdgcn_readfirstlane(col[e + 2]);
        int s3 = __builtin_amdgcn_readfirstlane(col[e + 3]);
        float2 v0 = *reinterpret_cast<const float2*>(y + (size_t)s0 * 128 + lane * 2);
        float2 v1 = *reinterpret_cast<const float2*>(y + (size_t)s1 * 128 + lane * 2);
        float2 v2 = *reinterpret_cast<const float2*>(y + (size_t)s2 * 128 + lane * 2);
        float2 v3 = *reinterpret_cast<const float2*>(y + (size_t)s3 * 128 + lane * 2);
        a0.x += v0.x; a0.y += v0.y;
        a1.x += v1.x; a1.y += v1.y;
        a2.x += v2.x; a2.y += v2.y;
        a3.x += v3.x; a3.y += v3.y;
    }
    for (; e < end; ++e) {
        int s0 = __builtin_amdgcn_readfirstlane(col[e]);
        float2 v0 = *reinterpret_cast<const float2*>(y + (size_t)s0 * 128 + lane * 2);
        a0.x += v0.x; a0.y += v0.y;
    }
    float sx = (a0.x + a1.x) + (a2.x + a3.x);
    float sy = (a0.y + a1.y) + (a2.y + a3.y);

    float2 self = *reinterpret_cast<const float2*>(y + (size_t)wave * 128 + lane * 2);
    float2 bb   = *reinterpret_cast<const float2*>(b1 + lane * 2);
    float iv = inv[wave];
    float2 r;
    r.x = fmaxf(fmaf(sx + self.x, iv, bb.x), 0.0f);
    r.y = fmaxf(fmaf(sy + self.y, iv, bb.y), 0.0f);
    *reinterpret_cast<float2*>(h1 + (size_t)wave * 128 + lane * 2) = r;
}

// agg2: out[n] = (sum_src z[src] + z[n]) * inv[n] + b2, wave/node, 1 float/lane
__global__ void agg2_kernel(const float* __restrict__ z, const int* __restrict__ rowptr,
                            const int* __restrict__ col, const float* __restrict__ inv,
                            const float* __restrict__ b2, float* __restrict__ out, int N) {
    int wave = (blockIdx.x * blockDim.x + threadIdx.x) >> 6;
    if (wave >= N) return;
    int lane = threadIdx.x & 63;
    int start = rowptr[wave], end = rowptr[wave + 1];

    float a0 = 0, a1 = 0, a2 = 0, a3 = 0;
    int e = start;
    for (; e + 3 < end; e += 4) {
        int s0 = __builtin_amdgcn_readfirstlane(col[e]);
        int s1 = __builtin_amdgcn_readfirstlane(col[e + 1]);
        int s2 = __builtin_amdgcn_readfirstlane(col[e + 2]);
        int s3 = __builtin_amdgcn_readfirstlane(col[e + 3]);
        a0 += z[(size_t)s0 * 64 + lane];
        a1 += z[(size_t)s1 * 64 + lane];
        a2 += z[(size_t)s2 * 64 + lane];
        a3 += z[(size_t)s3 * 64 + lane];
    }
    for (; e < end; ++e) {
        int s0 = __builtin_amdgcn_readfirstlane(col[e]);
        a0 += z[(size_t)s0 * 64 + lane];
    }
    float s = (a0 + a1) + (a2 + a3);
    float r = fmaf(s + z[(size_t)wave * 64 + lane], inv[wave], b2[lane]);
    out[(size_t)wave * 64 + lane] = r;
}

// ---------------------------------------------------------------------------
extern "C" void kernel_launch(void* const* d_in, const int* in_sizes, int n_in,
                              void* d_out, int out_size, void* d_ws, size_t ws_size,
                              hipStream_t stream) {
    const float* x   = (const float*)d_in[0];
    const float* W1  = (const float*)d_in[1];
    const float* b1  = (const float*)d_in[2];
    const float* W2  = (const float*)d_in[3];
    const float* b2  = (const float*)d_in[4];
    const int* esrc  = (const int*)d_in[5];
    const int* edst  = (const int*)d_in[6];
    float* out = (float*)d_out;

    // workspace layout (~110 MB, same footprint as round 2)
    int*   rowptr = (int*)d_ws;                         // N+1
    int*   cnt    = rowptr + NN + 1;                    // N (reused as cursor)
    int*   col    = cnt + NN;                           // E
    int*   bsum   = col + NE;                           // 512
    float* inv    = (float*)(bsum + 512);               // N
    float* y1     = inv + NN;                           // N*128  (z aliases this later)
    float* h1     = y1 + (size_t)NN * 128;              // N*128
    float* z      = y1;                                 // N*64, reuses y1 space

    // ---- CSR build ----
    hipMemsetAsync(cnt, 0, NN * sizeof(int), stream);
    count_kernel<<<(NE + 255) / 256, 256, 0, stream>>>(edst, cnt, NE);
    blocksum_kernel<<<NB, 256, 0, stream>>>(cnt, bsum, NN);
    scanb_kernel<<<1, 512, 0, stream>>>(bsum, NB);
    rowptr_kernel<<<NB, 256, 0, stream>>>(cnt, bsum, rowptr, NN);
    cursor_inv_kernel<<<(NN + 255) / 256, 256, 0, stream>>>(rowptr, cnt, inv, NN);
    fill_kernel<<<(NE + 255) / 256, 256, 0, stream>>>(esrc, edst, cnt, col, NE);

    // ---- layer 1: y1 = x@W1, then h1 = relu((agg(y1)+y1)*inv + b1) ----
    gemm1_kernel<<<(NN + 7) / 8, 128, 0, stream>>>(x, W1, y1, NN);
    agg1_kernel<<<(NN + 3) / 4, 256, 0, stream>>>(y1, rowptr, col, inv, b1, h1, NN);

    // ---- layer 2: z = h1@W2, then out = (agg(z)+z)*inv + b2 ----
    gemm2_kernel<<<(NN + 31) / 32, 256, 0, stream>>>(h1, W2, z, NN);
    agg2_kernel<<<(NN + 3) / 4, 256, 0, stream>>>(z, rowptr, col, inv, b2, out, NN);
}

// Round 4
// 554.284 us; speedup vs baseline: 10.2943x; 1.2009x over previous
//
#include <hip/hip_runtime.h>

#define NN 100000
#define NE 1600000
#define NB ((NN + 255) / 256)   // 391 scan blocks

// ---------------------------------------------------------------------------
// bf16 helpers (round-to-nearest-even-ish)
__device__ __forceinline__ unsigned short f2bf(float f) {
    unsigned int u = __float_as_uint(f);
    u += 0x7FFFu + ((u >> 16) & 1u);
    return (unsigned short)(u >> 16);
}
__device__ __forceinline__ float bf_lo(unsigned int u) { return __uint_as_float(u << 16); }
__device__ __forceinline__ float bf_hi(unsigned int u) { return __uint_as_float(u & 0xFFFF0000u); }

// ---------------------------------------------------------------------------
// CSR build
__global__ void count_kernel(const int* __restrict__ dst, int* __restrict__ cnt, int E) {
    int e = blockIdx.x * blockDim.x + threadIdx.x;
    if (e < E) atomicAdd(&cnt[dst[e]], 1);
}

__global__ void blocksum_kernel(const int* __restrict__ cnt, int* __restrict__ bsum, int N) {
    __shared__ int s[256];
    int i = blockIdx.x * 256 + threadIdx.x;
    s[threadIdx.x] = (i < N) ? cnt[i] : 0;
    __syncthreads();
    for (int o = 128; o > 0; o >>= 1) {
        if (threadIdx.x < o) s[threadIdx.x] += s[threadIdx.x + o];
        __syncthreads();
    }
    if (threadIdx.x == 0) bsum[blockIdx.x] = s[0];
}

__global__ void scanb_kernel(int* __restrict__ bsum, int nb) {
    __shared__ int s[512];
    int t = threadIdx.x;
    s[t] = (t < nb) ? bsum[t] : 0;
    __syncthreads();
    for (int o = 1; o < 512; o <<= 1) {
        int v = (t >= o) ? s[t - o] : 0;
        __syncthreads();
        if (t >= o) s[t] += v;
        __syncthreads();
    }
    if (t < nb) bsum[t] = (t == 0) ? 0 : s[t - 1];   // exclusive
}

__global__ void rowptr_kernel(const int* __restrict__ cnt, const int* __restrict__ boff,
                              int* __restrict__ rowptr, int N) {
    __shared__ int s[256];
    int t = threadIdx.x;
    int i = blockIdx.x * 256 + t;
    int v = (i < N) ? cnt[i] : 0;
    s[t] = v;
    __syncthreads();
    for (int o = 1; o < 256; o <<= 1) {
        int u = (t >= o) ? s[t - o] : 0;
        __syncthreads();
        if (t >= o) s[t] += u;
        __syncthreads();
    }
    if (i < N) rowptr[i] = boff[blockIdx.x] + s[t] - v;
    if (i == N - 1) rowptr[N] = boff[blockIdx.x] + s[t];
}

__global__ void cursor_inv_kernel(const int* __restrict__ rowptr, int* __restrict__ cursor,
                                  float* __restrict__ inv, int N) {
    int n = blockIdx.x * blockDim.x + threadIdx.x;
    if (n < N) {
        int r0 = rowptr[n], r1 = rowptr[n + 1];
        cursor[n] = r0;
        inv[n] = 1.0f / (float)(r1 - r0 + 1);
    }
}

__global__ void fill_kernel(const int* __restrict__ src, const int* __restrict__ dst,
                            int* __restrict__ cursor, int* __restrict__ col, int E) {
    int e = blockIdx.x * blockDim.x + threadIdx.x;
    if (e < E) {
        int pos = atomicAdd(&cursor[dst[e]], 1);
        col[pos] = src[e];
    }
}

// ---------------------------------------------------------------------------
// GEMM1: ybf = bf16(x @ W1)   [N,128]x[128,128], 8 nodes/block, 128 threads
__global__ void gemm1_kernel(const float* __restrict__ x, const float* __restrict__ W1,
                             unsigned short* __restrict__ ybf, int N) {
    __shared__ float xs[8][128];
    const int j = threadIdx.x;
    const int nb = blockIdx.x * 8;

    #pragma unroll
    for (int m = 0; m < 8; ++m) xs[m][j] = x[(size_t)(nb + m) * 128 + j];
    __syncthreads();

    float acc[8];
    #pragma unroll
    for (int m = 0; m < 8; ++m) acc[m] = 0.0f;

    #pragma unroll 4
    for (int k = 0; k < 128; k += 4) {
        float w0 = W1[(k + 0) * 128 + j];
        float w1 = W1[(k + 1) * 128 + j];
        float w2 = W1[(k + 2) * 128 + j];
        float w3 = W1[(k + 3) * 128 + j];
        #pragma unroll
        for (int m = 0; m < 8; ++m) {
            float4 v = *reinterpret_cast<const float4*>(&xs[m][k]);
            acc[m] = fmaf(v.x, w0, acc[m]);
            acc[m] = fmaf(v.y, w1, acc[m]);
            acc[m] = fmaf(v.z, w2, acc[m]);
            acc[m] = fmaf(v.w, w3, acc[m]);
        }
    }

    #pragma unroll
    for (int m = 0; m < 8; ++m) ybf[(size_t)(nb + m) * 128 + j] = f2bf(acc[m]);
}

// GEMM2: zbf = bf16(h1 @ W2)   [N,128]x[128,64], 32 nodes/block, 256 threads
__global__ void gemm2_kernel(const float* __restrict__ h1, const float* __restrict__ W2,
                             unsigned short* __restrict__ zbf, int N) {
    __shared__ float hs[32][128];
    const int t = threadIdx.x;
    const int j = t & 63;
    const int grp = t >> 6;          // 0..3, 8 nodes each
    const int nb = blockIdx.x * 32;

    for (int i = t; i < 32 * 128; i += 256) {
        hs[i >> 7][i & 127] = h1[(size_t)nb * 128 + i];
    }
    __syncthreads();

    float acc[8];
    #pragma unroll
    for (int m = 0; m < 8; ++m) acc[m] = 0.0f;

    #pragma unroll 4
    for (int k = 0; k < 128; k += 4) {
        float w0 = W2[(k + 0) * 64 + j];
        float w1 = W2[(k + 1) * 64 + j];
        float w2 = W2[(k + 2) * 64 + j];
        float w3 = W2[(k + 3) * 64 + j];
        #pragma unroll
        for (int m = 0; m < 8; ++m) {
            float4 v = *reinterpret_cast<const float4*>(&hs[grp * 8 + m][k]);
            acc[m] = fmaf(v.x, w0, acc[m]);
            acc[m] = fmaf(v.y, w1, acc[m]);
            acc[m] = fmaf(v.z, w2, acc[m]);
            acc[m] = fmaf(v.w, w3, acc[m]);
        }
    }

    #pragma unroll
    for (int m = 0; m < 8; ++m) {
        zbf[(size_t)(nb + grp * 8 + m) * 64 + j] = f2bf(acc[m]);
    }
}

// ---------------------------------------------------------------------------
// agg1: h1[n] = relu((sum_src y[src] + y[n]) * inv[n] + b1)
// wave/node; lane holds features {2*lane, 2*lane+1}; bf16 gather (1 dword/lane/edge)
__global__ void agg1_kernel(const unsigned short* __restrict__ ybf,
                            const int* __restrict__ rowptr, const int* __restrict__ col,
                            const float* __restrict__ inv, const float* __restrict__ b1,
                            float* __restrict__ h1, int N) {
    int wave = (blockIdx.x * blockDim.x + threadIdx.x) >> 6;
    if (wave >= N) return;
    int lane = threadIdx.x & 63;
    int start = rowptr[wave], end = rowptr[wave + 1];
    const unsigned int* yb = (const unsigned int*)ybf;   // row stride = 64 uints

    float ax0 = 0, ay0 = 0, ax1 = 0, ay1 = 0, ax2 = 0, ay2 = 0, ax3 = 0, ay3 = 0;
    int e = start;
    for (; e + 3 < end; e += 4) {
        int s0 = __builtin_amdgcn_readfirstlane(col[e]);
        int s1 = __builtin_amdgcn_readfirstlane(col[e + 1]);
        int s2 = __builtin_amdgcn_readfirstlane(col[e + 2]);
        int s3 = __builtin_amdgcn_readfirstlane(col[e + 3]);
        unsigned int u0 = yb[(size_t)s0 * 64 + lane];
        unsigned int u1 = yb[(size_t)s1 * 64 + lane];
        unsigned int u2 = yb[(size_t)s2 * 64 + lane];
        unsigned int u3 = yb[(size_t)s3 * 64 + lane];
        ax0 += bf_lo(u0); ay0 += bf_hi(u0);
        ax1 += bf_lo(u1); ay1 += bf_hi(u1);
        ax2 += bf_lo(u2); ay2 += bf_hi(u2);
        ax3 += bf_lo(u3); ay3 += bf_hi(u3);
    }
    for (; e < end; ++e) {
        int s0 = __builtin_amdgcn_readfirstlane(col[e]);
        unsigned int u0 = yb[(size_t)s0 * 64 + lane];
        ax0 += bf_lo(u0); ay0 += bf_hi(u0);
    }
    float sx = (ax0 + ax1) + (ax2 + ax3);
    float sy = (ay0 + ay1) + (ay2 + ay3);

    unsigned int us = yb[(size_t)wave * 64 + lane];
    float2 bb = *reinterpret_cast<const float2*>(b1 + lane * 2);
    float iv = inv[wave];
    float2 r;
    r.x = fmaxf(fmaf(sx + bf_lo(us), iv, bb.x), 0.0f);
    r.y = fmaxf(fmaf(sy + bf_hi(us), iv, bb.y), 0.0f);
    *reinterpret_cast<float2*>(h1 + (size_t)wave * 128 + lane * 2) = r;
}

// agg2: out[n] = (sum_src z[src] + z[n]) * inv[n] + b2
// HALF-wave/node (32 lanes); lane holds features {2*lane, 2*lane+1}; bf16 gather
__global__ void agg2_kernel(const unsigned short* __restrict__ zbf,
                            const int* __restrict__ rowptr, const int* __restrict__ col,
                            const float* __restrict__ inv, const float* __restrict__ b2,
                            float* __restrict__ out, int N) {
    int node = (blockIdx.x * blockDim.x + threadIdx.x) >> 5;
    if (node >= N) return;
    int lane = threadIdx.x & 31;
    int start = rowptr[node], end = rowptr[node + 1];
    const unsigned int* zb = (const unsigned int*)zbf;   // row stride = 32 uints

    float ax0 = 0, ay0 = 0, ax1 = 0, ay1 = 0, ax2 = 0, ay2 = 0, ax3 = 0, ay3 = 0;
    int e = start;
    for (; e + 3 < end; e += 4) {
        int s0 = col[e], s1 = col[e + 1], s2 = col[e + 2], s3 = col[e + 3];
        unsigned int u0 = zb[(size_t)s0 * 32 + lane];
        unsigned int u1 = zb[(size_t)s1 * 32 + lane];
        unsigned int u2 = zb[(size_t)s2 * 32 + lane];
        unsigned int u3 = zb[(size_t)s3 * 32 + lane];
        ax0 += bf_lo(u0); ay0 += bf_hi(u0);
        ax1 += bf_lo(u1); ay1 += bf_hi(u1);
        ax2 += bf_lo(u2); ay2 += bf_hi(u2);
        ax3 += bf_lo(u3); ay3 += bf_hi(u3);
    }
    for (; e < end; ++e) {
        unsigned int u0 = zb[(size_t)col[e] * 32 + lane];
        ax0 += bf_lo(u0); ay0 += bf_hi(u0);
    }
    float sx = (ax0 + ax1) + (ax2 + ax3);
    float sy = (ay0 + ay1) + (ay2 + ay3);

    unsigned int us = zb[(size_t)node * 32 + lane];
    float2 bb = *reinterpret_cast<const float2*>(b2 + lane * 2);
    float iv = inv[node];
    float2 r;
    r.x = fmaf(sx + bf_lo(us), iv, bb.x);
    r.y = fmaf(sy + bf_hi(us), iv, bb.y);
    *reinterpret_cast<float2*>(out + (size_t)node * 64 + lane * 2) = r;
}

// ---------------------------------------------------------------------------
extern "C" void kernel_launch(void* const* d_in, const int* in_sizes, int n_in,
                              void* d_out, int out_size, void* d_ws, size_t ws_size,
                              hipStream_t stream) {
    const float* x   = (const float*)d_in[0];
    const float* W1  = (const float*)d_in[1];
    const float* b1  = (const float*)d_in[2];
    const float* W2  = (const float*)d_in[3];
    const float* b2  = (const float*)d_in[4];
    const int* esrc  = (const int*)d_in[5];
    const int* edst  = (const int*)d_in[6];
    float* out = (float*)d_out;

    // workspace layout
    int*   rowptr = (int*)d_ws;                              // N+1
    int*   cnt    = rowptr + NN + 1;                         // N (reused as cursor)
    int*   col    = cnt + NN;                                // E
    int*   bsum   = col + NE;                                // 512
    float* inv    = (float*)(bsum + 512);                    // N
    unsigned short* ybf = (unsigned short*)(inv + NN);       // N*128 bf16 (25.6 MB)
    unsigned short* zbf = ybf + (size_t)NN * 128;            // N*64 bf16 (12.8 MB)
    float* h1     = (float*)(zbf + (size_t)NN * 64);         // N*128 fp32 (51.2 MB)

    // ---- CSR build ----
    hipMemsetAsync(cnt, 0, NN * sizeof(int), stream);
    count_kernel<<<(NE + 255) / 256, 256, 0, stream>>>(edst, cnt, NE);
    blocksum_kernel<<<NB, 256, 0, stream>>>(cnt, bsum, NN);
    scanb_kernel<<<1, 512, 0, stream>>>(bsum, NB);
    rowptr_kernel<<<NB, 256, 0, stream>>>(cnt, bsum, rowptr, NN);
    cursor_inv_kernel<<<(NN + 255) / 256, 256, 0, stream>>>(rowptr, cnt, inv, NN);
    fill_kernel<<<(NE + 255) / 256, 256, 0, stream>>>(esrc, edst, cnt, col, NE);

    // ---- layer 1: ybf = bf16(x@W1); h1 = relu((agg(y)+y)*inv + b1) ----
    gemm1_kernel<<<NN / 8, 128, 0, stream>>>(x, W1, ybf, NN);
    agg1_kernel<<<NN / 4, 256, 0, stream>>>(ybf, rowptr, col, inv, b1, h1, NN);

    // ---- layer 2: zbf = bf16(h1@W2); out = (agg(z)+z)*inv + b2 ----
    gemm2_kernel<<<(NN + 31) / 32, 256, 0, stream>>>(h1, W2, zbf, NN);
    agg2_kernel<<<NN / 8, 256, 0, stream>>>(zbf, rowptr, col, inv, b2, out, NN);
}

// Round 7
// 422.279 us; speedup vs baseline: 13.5123x; 1.3126x over previous
//
#include <hip/hip_runtime.h>

#define NN 100000
#define NE 1600000
#define NBUC 782          // ceil(100000/128) buckets of 128 dst nodes
#define NBLKA 256         // binning blocks
#define CHA 6250          // edges per binning block (256*6250 = 1.6M exactly)
#define LG (NBUC * NBLKA) // 200192 = 391*512 exactly

// ---------------------------------------------------------------------------
// bf16 helpers
__device__ __forceinline__ unsigned short f2bf(float f) {
    unsigned int u = __float_as_uint(f);
    u += 0x7FFFu + ((u >> 16) & 1u);
    return (unsigned short)(u >> 16);
}
__device__ __forceinline__ float bf_lo(unsigned int u) { return __uint_as_float(u << 16); }
__device__ __forceinline__ float bf_hi(unsigned int u) { return __uint_as_float(u & 0xFFFF0000u); }

// ---------------------------------------------------------------------------
// Pass A: per-block bucket histogram -> G[bucket][block]
__global__ void binA_kernel(const int* __restrict__ dst, int* __restrict__ G, int E) {
    __shared__ int hist[NBUC];
    int t = threadIdx.x;
    for (int i = t; i < NBUC; i += 256) hist[i] = 0;
    __syncthreads();
    int s0 = blockIdx.x * CHA;
    int s1 = min(E, s0 + CHA);
    for (int i = s0 + t; i < s1; i += 256) atomicAdd(&hist[dst[i] >> 7], 1);
    __syncthreads();
    for (int i = t; i < NBUC; i += 256) G[i * NBLKA + blockIdx.x] = hist[i];
}

// scan helpers over flattened G (length LG = 391*512)
__global__ void gsum_kernel(const int* __restrict__ G, int* __restrict__ gb) {
    __shared__ int s[512];
    int t = threadIdx.x;
    s[t] = G[blockIdx.x * 512 + t];
    __syncthreads();
    for (int o = 256; o > 0; o >>= 1) {
        if (t < o) s[t] += s[t + o];
        __syncthreads();
    }
    if (t == 0) gb[blockIdx.x] = s[0];
}

__global__ void scanb_kernel(int* __restrict__ bsum, int nb) {
    __shared__ int s[512];
    int t = threadIdx.x;
    s[t] = (t < nb) ? bsum[t] : 0;
    __syncthreads();
    for (int o = 1; o < 512; o <<= 1) {
        int v = (t >= o) ? s[t - o] : 0;
        __syncthreads();
        if (t >= o) s[t] += v;
        __syncthreads();
    }
    if (t < nb) bsum[t] = (t == 0) ? 0 : s[t - 1];   // exclusive
}

__global__ void gscan_kernel(int* __restrict__ G, const int* __restrict__ gb) {
    __shared__ int s[512];
    int t = threadIdx.x;
    int i = blockIdx.x * 512 + t;
    int v = G[i];
    s[t] = v;
    __syncthreads();
    for (int o = 1; o < 512; o <<= 1) {
        int u = (t >= o) ? s[t - o] : 0;
        __syncthreads();
        if (t >= o) s[t] += u;
        __syncthreads();
    }
    G[i] = gb[blockIdx.x] + s[t] - v;   // exclusive
}

// Pass B: place packed (dst,src) into bucket-grouped ebuf via LDS cursors
__global__ void binB_kernel(const int* __restrict__ src, const int* __restrict__ dst,
                            const int* __restrict__ G, unsigned long long* __restrict__ ebuf,
                            int E) {
    __shared__ int cur[NBUC];
    int t = threadIdx.x;
    for (int i = t; i < NBUC; i += 256) cur[i] = G[i * NBLKA + blockIdx.x];
    __syncthreads();
    int s0 = blockIdx.x * CHA;
    int s1 = min(E, s0 + CHA);
    for (int i = s0 + t; i < s1; i += 256) {
        int d = dst[i];
        int b = d >> 7;
        int pos = atomicAdd(&cur[b], 1);
        ebuf[pos] = ((unsigned long long)(unsigned int)d << 32) | (unsigned int)src[i];
    }
}

// Pass C: per-bucket node-level fill; also emits rowptr and inv
__global__ void fillC_kernel(const unsigned long long* __restrict__ ebuf,
                             const int* __restrict__ G, int* __restrict__ rowptr,
                             float* __restrict__ inv, int* __restrict__ col, int E, int N) {
    __shared__ int cnt[128];
    __shared__ int sc[128];
    int b = blockIdx.x;
    int t = threadIdx.x;
    int segStart = G[b * NBLKA];
    int segEnd = (b + 1 < NBUC) ? G[(b + 1) * NBLKA] : E;
    int nodeBase = b << 7;

    if (t < 128) cnt[t] = 0;
    __syncthreads();
    for (int i = segStart + t; i < segEnd; i += 256) {
        int d = (int)(ebuf[i] >> 32);
        atomicAdd(&cnt[d - nodeBase], 1);
    }
    __syncthreads();
    if (t < 128) sc[t] = cnt[t];
    __syncthreads();
    for (int o = 1; o < 128; o <<= 1) {
        int v = 0;
        if (t < 128 && t >= o) v = sc[t - o];
        __syncthreads();
        if (t < 128 && t >= o) sc[t] += v;
        __syncthreads();
    }
    if (t < 128) {
        int excl = (t == 0) ? 0 : sc[t - 1];
        int n = nodeBase + t;
        if (n < N) {
            rowptr[n] = segStart + excl;
            inv[n] = 1.0f / (float)(cnt[t] + 1);
        }
        sc[t] = segStart + excl;   // becomes cursor
    }
    if (b == 0 && t == 0) rowptr[N] = E;
    __syncthreads();
    for (int i = segStart + t; i < segEnd; i += 256) {
        unsigned long long p = ebuf[i];
        int d = (int)(p >> 32);
        int s = (int)(p & 0xFFFFFFFFull);
        int pos = atomicAdd(&sc[d - nodeBase], 1);
        col[pos] = s;
    }
}

// ---------------------------------------------------------------------------
// GEMM1: ybf = bf16(x @ W1)   [N,128]x[128,128], 8 nodes/block, 128 threads
__global__ void gemm1_kernel(const float* __restrict__ x, const float* __restrict__ W1,
                             unsigned short* __restrict__ ybf, int N) {
    __shared__ float xs[8][128];
    const int j = threadIdx.x;
    const int nb = blockIdx.x * 8;

    #pragma unroll
    for (int m = 0; m < 8; ++m) xs[m][j] = x[(size_t)(nb + m) * 128 + j];
    __syncthreads();

    float acc[8];
    #pragma unroll
    for (int m = 0; m < 8; ++m) acc[m] = 0.0f;

    #pragma unroll 4
    for (int k = 0; k < 128; k += 4) {
        float w0 = W1[(k + 0) * 128 + j];
        float w1 = W1[(k + 1) * 128 + j];
        float w2 = W1[(k + 2) * 128 + j];
        float w3 = W1[(k + 3) * 128 + j];
        #pragma unroll
        for (int m = 0; m < 8; ++m) {
            float4 v = *reinterpret_cast<const float4*>(&xs[m][k]);
            acc[m] = fmaf(v.x, w0, acc[m]);
            acc[m] = fmaf(v.y, w1, acc[m]);
            acc[m] = fmaf(v.z, w2, acc[m]);
            acc[m] = fmaf(v.w, w3, acc[m]);
        }
    }

    #pragma unroll
    for (int m = 0; m < 8; ++m) ybf[(size_t)(nb + m) * 128 + j] = f2bf(acc[m]);
}

// GEMM2: zbf = bf16(h1 @ W2)   [N,128]x[128,64], 32 nodes/block, 256 threads
__global__ void gemm2_kernel(const float* __restrict__ h1, const float* __restrict__ W2,
                             unsigned short* __restrict__ zbf, int N) {
    __shared__ float hs[32][128];
    const int t = threadIdx.x;
    const int j = t & 63;
    const int grp = t >> 6;
    const int nb = blockIdx.x * 32;

    for (int i = t; i < 32 * 128; i += 256) {
        hs[i >> 7][i & 127] = h1[(size_t)nb * 128 + i];
    }
    __syncthreads();

    float acc[8];
    #pragma unroll
    for (int m = 0; m < 8; ++m) acc[m] = 0.0f;

    #pragma unroll 4
    for (int k = 0; k < 128; k += 4) {
        float w0 = W2[(k + 0) * 64 + j];
        float w1 = W2[(k + 1) * 64 + j];
        float w2 = W2[(k + 2) * 64 + j];
        float w3 = W2[(k + 3) * 64 + j];
        #pragma unroll
        for (int m = 0; m < 8; ++m) {
            float4 v = *reinterpret_cast<const float4*>(&hs[grp * 8 + m][k]);
            acc[m] = fmaf(v.x, w0, acc[m]);
            acc[m] = fmaf(v.y, w1, acc[m]);
            acc[m] = fmaf(v.z, w2, acc[m]);
            acc[m] = fmaf(v.w, w3, acc[m]);
        }
    }

    #pragma unroll
    for (int m = 0; m < 8; ++m) {
        zbf[(size_t)(nb + grp * 8 + m) * 64 + j] = f2bf(acc[m]);
    }
}

// ---------------------------------------------------------------------------
// agg1: h1[n] = relu((sum_src y[src] + y[n]) * inv[n] + b1); wave/node; bf16 gather
__global__ void agg1_kernel(const unsigned short* __restrict__ ybf,
                            const int* __restrict__ rowptr, const int* __restrict__ col,
                            const float* __restrict__ inv, const float* __restrict__ b1,
                            float* __restrict__ h1, int N) {
    int wave = (blockIdx.x * blockDim.x + threadIdx.x) >> 6;
    if (wave >= N) return;
    int lane = threadIdx.x & 63;
    int start = rowptr[wave], end = rowptr[wave + 1];
    const unsigned int* yb = (const unsigned int*)ybf;   // row stride 64 uints

    float ax0 = 0, ay0 = 0, ax1 = 0, ay1 = 0, ax2 = 0, ay2 = 0, ax3 = 0, ay3 = 0;
    int e = start;
    for (; e + 3 < end; e += 4) {
        int s0 = __builtin_amdgcn_readfirstlane(col[e]);
        int s1 = __builtin_amdgcn_readfirstlane(col[e + 1]);
        int s2 = __builtin_amdgcn_readfirstlane(col[e + 2]);
        int s3 = __builtin_amdgcn_readfirstlane(col[e + 3]);
        unsigned int u0 = yb[(size_t)s0 * 64 + lane];
        unsigned int u1 = yb[(size_t)s1 * 64 + lane];
        unsigned int u2 = yb[(size_t)s2 * 64 + lane];
        unsigned int u3 = yb[(size_t)s3 * 64 + lane];
        ax0 += bf_lo(u0); ay0 += bf_hi(u0);
        ax1 += bf_lo(u1); ay1 += bf_hi(u1);
        ax2 += bf_lo(u2); ay2 += bf_hi(u2);
        ax3 += bf_lo(u3); ay3 += bf_hi(u3);
    }
    for (; e < end; ++e) {
        int s0 = __builtin_amdgcn_readfirstlane(col[e]);
        unsigned int u0 = yb[(size_t)s0 * 64 + lane];
        ax0 += bf_lo(u0); ay0 += bf_hi(u0);
    }
    float sx = (ax0 + ax1) + (ax2 + ax3);
    float sy = (ay0 + ay1) + (ay2 + ay3);

    unsigned int us = yb[(size_t)wave * 64 + lane];
    float2 bb = *reinterpret_cast<const float2*>(b1 + lane * 2);
    float iv = inv[wave];
    float2 r;
    r.x = fmaxf(fmaf(sx + bf_lo(us), iv, bb.x), 0.0f);
    r.y = fmaxf(fmaf(sy + bf_hi(us), iv, bb.y), 0.0f);
    *reinterpret_cast<float2*>(h1 + (size_t)wave * 128 + lane * 2) = r;
}

// agg2: out[n] = (sum_src z[src] + z[n]) * inv[n] + b2; half-wave/node; bf16 gather
__global__ void agg2_kernel(const unsigned short* __restrict__ zbf,
                            const int* __restrict__ rowptr, const int* __restrict__ col,
                            const float* __restrict__ inv, const float* __restrict__ b2,
                            float* __restrict__ out, int N) {
    int node = (blockIdx.x * blockDim.x + threadIdx.x) >> 5;
    if (node >= N) return;
    int lane = threadIdx.x & 31;
    int start = rowptr[node], end = rowptr[node + 1];
    const unsigned int* zb = (const unsigned int*)zbf;   // row stride 32 uints

    float ax0 = 0, ay0 = 0, ax1 = 0, ay1 = 0, ax2 = 0, ay2 = 0, ax3 = 0, ay3 = 0;
    int e = start;
    for (; e + 3 < end; e += 4) {
        int s0 = col[e], s1 = col[e + 1], s2 = col[e + 2], s3 = col[e + 3];
        unsigned int u0 = zb[(size_t)s0 * 32 + lane];
        unsigned int u1 = zb[(size_t)s1 * 32 + lane];
        unsigned int u2 = zb[(size_t)s2 * 32 + lane];
        unsigned int u3 = zb[(size_t)s3 * 32 + lane];
        ax0 += bf_lo(u0); ay0 += bf_hi(u0);
        ax1 += bf_lo(u1); ay1 += bf_hi(u1);
        ax2 += bf_lo(u2); ay2 += bf_hi(u2);
        ax3 += bf_lo(u3); ay3 += bf_hi(u3);
    }
    for (; e < end; ++e) {
        unsigned int u0 = zb[(size_t)col[e] * 32 + lane];
        ax0 += bf_lo(u0); ay0 += bf_hi(u0);
    }
    float sx = (ax0 + ax1) + (ax2 + ax3);
    float sy = (ay0 + ay1) + (ay2 + ay3);

    unsigned int us = zb[(size_t)node * 32 + lane];
    float2 bb = *reinterpret_cast<const float2*>(b2 + lane * 2);
    float iv = inv[node];
    float2 r;
    r.x = fmaf(sx + bf_lo(us), iv, bb.x);
    r.y = fmaf(sy + bf_hi(us), iv, bb.y);
    *reinterpret_cast<float2*>(out + (size_t)node * 64 + lane * 2) = r;
}

// ---------------------------------------------------------------------------
extern "C" void kernel_launch(void* const* d_in, const int* in_sizes, int n_in,
                              void* d_out, int out_size, void* d_ws, size_t ws_size,
                              hipStream_t stream) {
    const float* x   = (const float*)d_in[0];
    const float* W1  = (const float*)d_in[1];
    const float* b1  = (const float*)d_in[2];
    const float* W2  = (const float*)d_in[3];
    const float* b2  = (const float*)d_in[4];
    const int* esrc  = (const int*)d_in[5];
    const int* edst  = (const int*)d_in[6];
    float* out = (float*)d_out;

    // workspace layout (8B-aligned first)
    unsigned long long* ebuf = (unsigned long long*)d_ws;        // E (12.8 MB)
    int*   G      = (int*)(ebuf + NE);                           // LG = 200192
    int*   gb     = G + LG;                                      // 512
    int*   rowptr = gb + 512;                                    // N+1
    int*   col    = rowptr + NN + 1;                             // E
    float* inv    = (float*)(col + NE);                          // N
    unsigned short* ybf = (unsigned short*)(inv + NN);           // N*128 bf16
    unsigned short* zbf = ybf + (size_t)NN * 128;                // N*64 bf16
    float* h1     = (float*)(zbf + (size_t)NN * 64);             // N*128 fp32

    // ---- CSR build via LDS-binned bucket sort (no global atomics) ----
    binA_kernel<<<NBLKA, 256, 0, stream>>>(edst, G, NE);
    gsum_kernel<<<LG / 512, 512, 0, stream>>>(G, gb);
    scanb_kernel<<<1, 512, 0, stream>>>(gb, LG / 512);
    gscan_kernel<<<LG / 512, 512, 0, stream>>>(G, gb);
    binB_kernel<<<NBLKA, 256, 0, stream>>>(esrc, edst, G, ebuf, NE);
    fillC_kernel<<<NBUC, 256, 0, stream>>>(ebuf, G, rowptr, inv, col, NE, NN);

    // ---- layer 1: ybf = bf16(x@W1); h1 = relu((agg(y)+y)*inv + b1) ----
    gemm1_kernel<<<NN / 8, 128, 0, stream>>>(x, W1, ybf, NN);
    agg1_kernel<<<NN / 4, 256, 0, stream>>>(ybf, rowptr, col, inv, b1, h1, NN);

    // ---- layer 2: zbf = bf16(h1@W2); out = (agg(z)+z)*inv + b2 ----
    gemm2_kernel<<<(NN + 31) / 32, 256, 0, stream>>>(h1, W2, zbf, NN);
    agg2_kernel<<<NN / 8, 256, 0, stream>>>(zbf, rowptr, col, inv, b2, out, NN);
}

// Round 8
// 418.996 us; speedup vs baseline: 13.6181x; 1.0078x over previous
//
#include <hip/hip_runtime.h>

#define NN 100000
#define NNP 100032        // padded to multiple of 64 rows for MFMA tiles
#define NE 1600000
#define NBUC 782          // ceil(100000/128) buckets of 128 dst nodes
#define NBLKA 256         // binning blocks
#define CHA 6250          // edges per binning block (256*6250 = 1.6M exactly)
#define LG (NBUC * NBLKA) // 200192 = 391*512 exactly

typedef __attribute__((ext_vector_type(8))) short short8;   // 8 bf16 (4 VGPRs)
typedef __attribute__((ext_vector_type(4))) float f32x4;

// ---------------------------------------------------------------------------
// bf16 helpers
__device__ __forceinline__ unsigned short f2bf(float f) {
    unsigned int u = __float_as_uint(f);
    u += 0x7FFFu + ((u >> 16) & 1u);
    return (unsigned short)(u >> 16);
}
__device__ __forceinline__ float ubf(unsigned short h) {
    return __uint_as_float((unsigned int)h << 16);
}
__device__ __forceinline__ float bf_lo(unsigned int u) { return __uint_as_float(u << 16); }
__device__ __forceinline__ float bf_hi(unsigned int u) { return __uint_as_float(u & 0xFFFF0000u); }

// ---------------------------------------------------------------------------
// convert x -> bf16 hi/lo split (each thread: one float4)
__global__ void convx_kernel(const float* __restrict__ x, unsigned short* __restrict__ xh,
                             unsigned short* __restrict__ xl) {
    int t = blockIdx.x * 256 + threadIdx.x;          // < NN*32
    float4 v = reinterpret_cast<const float4*>(x)[t];
    ushort4 h, l;
    h.x = f2bf(v.x); l.x = f2bf(v.x - ubf(h.x));
    h.y = f2bf(v.y); l.y = f2bf(v.y - ubf(h.y));
    h.z = f2bf(v.z); l.z = f2bf(v.z - ubf(h.z));
    h.w = f2bf(v.w); l.w = f2bf(v.w - ubf(h.w));
    reinterpret_cast<ushort4*>(xh)[t] = h;
    reinterpret_cast<ushort4*>(xl)[t] = l;
}

// transpose + split weights: w1t[n][k], w2t[n][k]
__global__ void convw_kernel(const float* __restrict__ W1, const float* __restrict__ W2,
                             unsigned short* __restrict__ w1th, unsigned short* __restrict__ w1tl,
                             unsigned short* __restrict__ w2th, unsigned short* __restrict__ w2tl) {
    int n = blockIdx.x;       // 0..191
    int k = threadIdx.x;      // 0..127
    if (n < 128) {
        float w = W1[k * 128 + n];
        unsigned short h = f2bf(w);
        w1th[n * 128 + k] = h;
        w1tl[n * 128 + k] = f2bf(w - ubf(h));
    } else {
        int n2 = n - 128;
        float w = W2[k * 64 + n2];
        unsigned short h = f2bf(w);
        w2th[n2 * 128 + k] = h;
        w2tl[n2 * 128 + k] = f2bf(w - ubf(h));
    }
}

// ---------------------------------------------------------------------------
// Pass A: per-block bucket histogram -> G[bucket][block]
__global__ void binA_kernel(const int* __restrict__ dst, int* __restrict__ G, int E) {
    __shared__ int hist[NBUC];
    int t = threadIdx.x;
    for (int i = t; i < NBUC; i += 256) hist[i] = 0;
    __syncthreads();
    int s0 = blockIdx.x * CHA;
    int s1 = min(E, s0 + CHA);
    for (int i = s0 + t; i < s1; i += 256) atomicAdd(&hist[dst[i] >> 7], 1);
    __syncthreads();
    for (int i = t; i < NBUC; i += 256) G[i * NBLKA + blockIdx.x] = hist[i];
}

__global__ void gsum_kernel(const int* __restrict__ G, int* __restrict__ gb) {
    __shared__ int s[512];
    int t = threadIdx.x;
    s[t] = G[blockIdx.x * 512 + t];
    __syncthreads();
    for (int o = 256; o > 0; o >>= 1) {
        if (t < o) s[t] += s[t + o];
        __syncthreads();
    }
    if (t == 0) gb[blockIdx.x] = s[0];
}

__global__ void scanb_kernel(int* __restrict__ bsum, int nb) {
    __shared__ int s[512];
    int t = threadIdx.x;
    s[t] = (t < nb) ? bsum[t] : 0;
    __syncthreads();
    for (int o = 1; o < 512; o <<= 1) {
        int v = (t >= o) ? s[t - o] : 0;
        __syncthreads();
        if (t >= o) s[t] += v;
        __syncthreads();
    }
    if (t < nb) bsum[t] = (t == 0) ? 0 : s[t - 1];   // exclusive
}

__global__ void gscan_kernel(int* __restrict__ G, const int* __restrict__ gb) {
    __shared__ int s[512];
    int t = threadIdx.x;
    int i = blockIdx.x * 512 + t;
    int v = G[i];
    s[t] = v;
    __syncthreads();
    for (int o = 1; o < 512; o <<= 1) {
        int u = (t >= o) ? s[t - o] : 0;
        __syncthreads();
        if (t >= o) s[t] += u;
        __syncthreads();
    }
    G[i] = gb[blockIdx.x] + s[t] - v;   // exclusive
}

// Pass B: place packed (dst,src) into bucket-grouped ebuf via LDS cursors
__global__ void binB_kernel(const int* __restrict__ src, const int* __restrict__ dst,
                            const int* __restrict__ G, unsigned long long* __restrict__ ebuf,
                            int E) {
    __shared__ int cur[NBUC];
    int t = threadIdx.x;
    for (int i = t; i < NBUC; i += 256) cur[i] = G[i * NBLKA + blockIdx.x];
    __syncthreads();
    int s0 = blockIdx.x * CHA;
    int s1 = min(E, s0 + CHA);
    for (int i = s0 + t; i < s1; i += 256) {
        int d = dst[i];
        int b = d >> 7;
        int pos = atomicAdd(&cur[b], 1);
        ebuf[pos] = ((unsigned long long)(unsigned int)d << 32) | (unsigned int)src[i];
    }
}

// Pass C: per-bucket node-level fill; also emits rowptr and inv
__global__ void fillC_kernel(const unsigned long long* __restrict__ ebuf,
                             const int* __restrict__ G, int* __restrict__ rowptr,
                             float* __restrict__ inv, int* __restrict__ col, int E, int N) {
    __shared__ int cnt[128];
    __shared__ int sc[128];
    int b = blockIdx.x;
    int t = threadIdx.x;
    int segStart = G[b * NBLKA];
    int segEnd = (b + 1 < NBUC) ? G[(b + 1) * NBLKA] : E;
    int nodeBase = b << 7;

    if (t < 128) cnt[t] = 0;
    __syncthreads();
    for (int i = segStart + t; i < segEnd; i += 256) {
        int d = (int)(ebuf[i] >> 32);
        atomicAdd(&cnt[d - nodeBase], 1);
    }
    __syncthreads();
    if (t < 128) sc[t] = cnt[t];
    __syncthreads();
    for (int o = 1; o < 128; o <<= 1) {
        int v = 0;
        if (t < 128 && t >= o) v = sc[t - o];
        __syncthreads();
        if (t < 128 && t >= o) sc[t] += v;
        __syncthreads();
    }
    if (t < 128) {
        int excl = (t == 0) ? 0 : sc[t - 1];
        int n = nodeBase + t;
        if (n < N) {
            rowptr[n] = segStart + excl;
            inv[n] = 1.0f / (float)(cnt[t] + 1);
        }
        sc[t] = segStart + excl;   // becomes cursor
    }
    if (b == 0 && t == 0) rowptr[N] = E;
    __syncthreads();
    for (int i = segStart + t; i < segEnd; i += 256) {
        unsigned long long p = ebuf[i];
        int d = (int)(p >> 32);
        int s = (int)(p & 0xFFFFFFFFull);
        int pos = atomicAdd(&sc[d - nodeBase], 1);
        col[pos] = s;
    }
}

// ---------------------------------------------------------------------------
// MFMA GEMM1: ybf = bf16( (xh+xl) @ (Wh+Wl) ), error-compensated 3-term
// block = 256 (4 waves), 64 rows/block, wave = 16 rows x 128 cols
__global__ __launch_bounds__(256) void gemm1m_kernel(
    const unsigned short* __restrict__ xh, const unsigned short* __restrict__ xl,
    const unsigned short* __restrict__ w1th, const unsigned short* __restrict__ w1tl,
    unsigned short* __restrict__ ybf) {
    const int wid = threadIdx.x >> 6;
    const int lane = threadIdx.x & 63;
    const int rbase = blockIdx.x * 64 + wid * 16;
    const int r = lane & 15;
    const int kg = lane >> 4;          // 0..3

    f32x4 acc[8];
    #pragma unroll
    for (int j = 0; j < 8; ++j) acc[j] = (f32x4){0.0f, 0.0f, 0.0f, 0.0f};

    const short* xhp = (const short*)xh;
    const short* xlp = (const short*)xl;
    const short* wh  = (const short*)w1th;
    const short* wl  = (const short*)w1tl;

    #pragma unroll
    for (int kk = 0; kk < 4; ++kk) {
        const int ko = kk * 32 + kg * 8;
        short8 a_h = *reinterpret_cast<const short8*>(xhp + (size_t)(rbase + r) * 128 + ko);
        short8 a_l = *reinterpret_cast<const short8*>(xlp + (size_t)(rbase + r) * 128 + ko);
        #pragma unroll
        for (int j = 0; j < 8; ++j) {
            short8 b_h = *reinterpret_cast<const short8*>(wh + (j * 16 + r) * 128 + ko);
            short8 b_l = *reinterpret_cast<const short8*>(wl + (j * 16 + r) * 128 + ko);
            acc[j] = __builtin_amdgcn_mfma_f32_16x16x32_bf16(a_h, b_h, acc[j], 0, 0, 0);
            acc[j] = __builtin_amdgcn_mfma_f32_16x16x32_bf16(a_h, b_l, acc[j], 0, 0, 0);
            acc[j] = __builtin_amdgcn_mfma_f32_16x16x32_bf16(a_l, b_h, acc[j], 0, 0, 0);
        }
    }

    // C/D layout: col = lane&15, row = (lane>>4)*4 + reg   [m89-verified]
    #pragma unroll
    for (int j = 0; j < 8; ++j) {
        #pragma unroll
        for (int q = 0; q < 4; ++q) {
            ybf[(size_t)(rbase + kg * 4 + q) * 128 + j * 16 + r] = f2bf(acc[j][q]);
        }
    }
}

// MFMA GEMM2: zbf = bf16( (h1h+h1l) @ (W2h+W2l) ), N=64
__global__ __launch_bounds__(256) void gemm2m_kernel(
    const unsigned short* __restrict__ h1h, const unsigned short* __restrict__ h1l,
    const unsigned short* __restrict__ w2th, const unsigned short* __restrict__ w2tl,
    unsigned short* __restrict__ zbf) {
    const int wid = threadIdx.x >> 6;
    const int lane = threadIdx.x & 63;
    const int rbase = blockIdx.x * 64 + wid * 16;
    const int r = lane & 15;
    const int kg = lane >> 4;

    f32x4 acc[4];
    #pragma unroll
    for (int j = 0; j < 4; ++j) acc[j] = (f32x4){0.0f, 0.0f, 0.0f, 0.0f};

    const short* hhp = (const short*)h1h;
    const short* hlp = (const short*)h1l;
    const short* wh  = (const short*)w2th;
    const short* wl  = (const short*)w2tl;

    #pragma unroll
    for (int kk = 0; kk < 4; ++kk) {
        const int ko = kk * 32 + kg * 8;
        short8 a_h = *reinterpret_cast<const short8*>(hhp + (size_t)(rbase + r) * 128 + ko);
        short8 a_l = *reinterpret_cast<const short8*>(hlp + (size_t)(rbase + r) * 128 + ko);
        #pragma unroll
        for (int j = 0; j < 4; ++j) {
            short8 b_h = *reinterpret_cast<const short8*>(wh + (j * 16 + r) * 128 + ko);
            short8 b_l = *reinterpret_cast<const short8*>(wl + (j * 16 + r) * 128 + ko);
            acc[j] = __builtin_amdgcn_mfma_f32_16x16x32_bf16(a_h, b_h, acc[j], 0, 0, 0);
            acc[j] = __builtin_amdgcn_mfma_f32_16x16x32_bf16(a_h, b_l, acc[j], 0, 0, 0);
            acc[j] = __builtin_amdgcn_mfma_f32_16x16x32_bf16(a_l, b_h, acc[j], 0, 0, 0);
        }
    }

    #pragma unroll
    for (int j = 0; j < 4; ++j) {
        #pragma unroll
        for (int q = 0; q < 4; ++q) {
            zbf[(size_t)(rbase + kg * 4 + q) * 64 + j * 16 + r] = f2bf(acc[j][q]);
        }
    }
}

// ---------------------------------------------------------------------------
// agg1: h1 = relu((sum_src y[src] + y[n]) * inv[n] + b1), emitted as bf16 hi/lo
__global__ void agg1_kernel(const unsigned short* __restrict__ ybf,
                            const int* __restrict__ rowptr, const int* __restrict__ col,
                            const float* __restrict__ inv, const float* __restrict__ b1,
                            unsigned short* __restrict__ h1h, unsigned short* __restrict__ h1l,
                            int N) {
    int wave = (blockIdx.x * blockDim.x + threadIdx.x) >> 6;
    if (wave >= N) return;
    int lane = threadIdx.x & 63;
    int start = rowptr[wave], end = rowptr[wave + 1];
    const unsigned int* yb = (const unsigned int*)ybf;   // row stride 64 uints

    float ax0 = 0, ay0 = 0, ax1 = 0, ay1 = 0, ax2 = 0, ay2 = 0, ax3 = 0, ay3 = 0;
    int e = start;
    for (; e + 3 < end; e += 4) {
        int s0 = __builtin_amdgcn_readfirstlane(col[e]);
        int s1 = __builtin_amdgcn_readfirstlane(col[e + 1]);
        int s2 = __builtin_amdgcn_readfirstlane(col[e + 2]);
        int s3 = __builtin_amdgcn_readfirstlane(col[e + 3]);
        unsigned int u0 = yb[(size_t)s0 * 64 + lane];
        unsigned int u1 = yb[(size_t)s1 * 64 + lane];
        unsigned int u2 = yb[(size_t)s2 * 64 + lane];
        unsigned int u3 = yb[(size_t)s3 * 64 + lane];
        ax0 += bf_lo(u0); ay0 += bf_hi(u0);
        ax1 += bf_lo(u1); ay1 += bf_hi(u1);
        ax2 += bf_lo(u2); ay2 += bf_hi(u2);
        ax3 += bf_lo(u3); ay3 += bf_hi(u3);
    }
    for (; e < end; ++e) {
        int s0 = __builtin_amdgcn_readfirstlane(col[e]);
        unsigned int u0 = yb[(size_t)s0 * 64 + lane];
        ax0 += bf_lo(u0); ay0 += bf_hi(u0);
    }
    float sx = (ax0 + ax1) + (ax2 + ax3);
    float sy = (ay0 + ay1) + (ay2 + ay3);

    unsigned int us = yb[(size_t)wave * 64 + lane];
    float2 bb = *reinterpret_cast<const float2*>(b1 + lane * 2);
    float iv = inv[wave];
    float rx = fmaxf(fmaf(sx + bf_lo(us), iv, bb.x), 0.0f);
    float ry = fmaxf(fmaf(sy + bf_hi(us), iv, bb.y), 0.0f);

    ushort2 h, l;
    h.x = f2bf(rx); l.x = f2bf(rx - ubf(h.x));
    h.y = f2bf(ry); l.y = f2bf(ry - ubf(h.y));
    *reinterpret_cast<ushort2*>(h1h + (size_t)wave * 128 + lane * 2) = h;
    *reinterpret_cast<ushort2*>(h1l + (size_t)wave * 128 + lane * 2) = l;
}

// agg2: out[n] = (sum_src z[src] + z[n]) * inv[n] + b2; half-wave/node; bf16 gather
__global__ void agg2_kernel(const unsigned short* __restrict__ zbf,
                            const int* __restrict__ rowptr, const int* __restrict__ col,
                            const float* __restrict__ inv, const float* __restrict__ b2,
                            float* __restrict__ out, int N) {
    int node = (blockIdx.x * blockDim.x + threadIdx.x) >> 5;
    if (node >= N) return;
    int lane = threadIdx.x & 31;
    int start = rowptr[node], end = rowptr[node + 1];
    const unsigned int* zb = (const unsigned int*)zbf;   // row stride 32 uints

    float ax0 = 0, ay0 = 0, ax1 = 0, ay1 = 0, ax2 = 0, ay2 = 0, ax3 = 0, ay3 = 0;
    int e = start;
    for (; e + 3 < end; e += 4) {
        int s0 = col[e], s1 = col[e + 1], s2 = col[e + 2], s3 = col[e + 3];
        unsigned int u0 = zb[(size_t)s0 * 32 + lane];
        unsigned int u1 = zb[(size_t)s1 * 32 + lane];
        unsigned int u2 = zb[(size_t)s2 * 32 + lane];
        unsigned int u3 = zb[(size_t)s3 * 32 + lane];
        ax0 += bf_lo(u0); ay0 += bf_hi(u0);
        ax1 += bf_lo(u1); ay1 += bf_hi(u1);
        ax2 += bf_lo(u2); ay2 += bf_hi(u2);
        ax3 += bf_lo(u3); ay3 += bf_hi(u3);
    }
    for (; e < end; ++e) {
        unsigned int u0 = zb[(size_t)col[e] * 32 + lane];
        ax0 += bf_lo(u0); ay0 += bf_hi(u0);
    }
    float sx = (ax0 + ax1) + (ax2 + ax3);
    float sy = (ay0 + ay1) + (ay2 + ay3);

    unsigned int us = zb[(size_t)node * 32 + lane];
    float2 bb = *reinterpret_cast<const float2*>(b2 + lane * 2);
    float iv = inv[node];
    float2 r;
    r.x = fmaf(sx + bf_lo(us), iv, bb.x);
    r.y = fmaf(sy + bf_hi(us), iv, bb.y);
    *reinterpret_cast<float2*>(out + (size_t)node * 64 + lane * 2) = r;
}

// ---------------------------------------------------------------------------
extern "C" void kernel_launch(void* const* d_in, const int* in_sizes, int n_in,
                              void* d_out, int out_size, void* d_ws, size_t ws_size,
                              hipStream_t stream) {
    const float* x   = (const float*)d_in[0];
    const float* W1  = (const float*)d_in[1];
    const float* b1  = (const float*)d_in[2];
    const float* W2  = (const float*)d_in[3];
    const float* b2  = (const float*)d_in[4];
    const int* esrc  = (const int*)d_in[5];
    const int* edst  = (const int*)d_in[6];
    float* out = (float*)d_out;

    // workspace layout (~97.7 MB). ebuf aliases ybf (ebuf dead before gemm1 writes ybf).
    char* p = (char*)d_ws;
    unsigned short* ybf = (unsigned short*)p;                 // NNP*128 bf16 (25.6 MB)
    unsigned long long* ebuf = (unsigned long long*)p;        // NE*8 = 12.8 MB (alias)
    p += (size_t)NNP * 128 * 2;
    int* G = (int*)p;        p += (size_t)LG * 4;             // 200192
    int* gb = (int*)p;       p += 512 * 4;
    int* rowptr = (int*)p;   p += (size_t)(NN + 4) * 4;       // padded for 16B alignment
    int* col = (int*)p;      p += (size_t)NE * 4;
    float* inv = (float*)p;  p += (size_t)NN * 4;
    unsigned short* w1th = (unsigned short*)p; p += 128 * 128 * 2;
    unsigned short* w1tl = (unsigned short*)p; p += 128 * 128 * 2;
    unsigned short* w2th = (unsigned short*)p; p += 64 * 128 * 2;
    unsigned short* w2tl = (unsigned short*)p; p += 64 * 128 * 2;
    unsigned short* xh = (unsigned short*)p;   p += (size_t)NNP * 128 * 2;  // h1h aliases
    unsigned short* xl = (unsigned short*)p;   p += (size_t)NNP * 128 * 2;  // h1l aliases
    unsigned short* zbf = (unsigned short*)p;  p += (size_t)NNP * 64 * 2;
    unsigned short* h1h = xh;   // x dead after gemm1
    unsigned short* h1l = xl;

    // zero pad rows (rows NN..NNP-1) of xh/xl so MFMA tail tiles read zeros
    size_t padOff = (size_t)NN * 128 * 2;
    size_t padBytes = (size_t)(NNP - NN) * 128 * 2;
    hipMemsetAsync(xh + (size_t)NN * 128, 0, padBytes, stream);
    hipMemsetAsync(xl + (size_t)NN * 128, 0, padBytes, stream);
    (void)padOff;

    // ---- input conversions ----
    convx_kernel<<<NN * 32 / 256, 256, 0, stream>>>(x, xh, xl);
    convw_kernel<<<192, 128, 0, stream>>>(W1, W2, w1th, w1tl, w2th, w2tl);

    // ---- CSR build via LDS-binned bucket sort ----
    binA_kernel<<<NBLKA, 256, 0, stream>>>(edst, G, NE);
    gsum_kernel<<<LG / 512, 512, 0, stream>>>(G, gb);
    scanb_kernel<<<1, 512, 0, stream>>>(gb, LG / 512);
    gscan_kernel<<<LG / 512, 512, 0, stream>>>(G, gb);
    binB_kernel<<<NBLKA, 256, 0, stream>>>(esrc, edst, G, ebuf, NE);
    fillC_kernel<<<NBUC, 256, 0, stream>>>(ebuf, G, rowptr, inv, col, NE, NN);

    // ---- layer 1: ybf = bf16(x@W1) via MFMA; h1(hi/lo) = relu((agg+self)*inv + b1) ----
    gemm1m_kernel<<<NNP / 64, 256, 0, stream>>>(xh, xl, w1th, w1tl, ybf);
    agg1_kernel<<<NN / 4, 256, 0, stream>>>(ybf, rowptr, col, inv, b1, h1h, h1l, NN);

    // pad rows of h1h/h1l were already zeroed (same buffers as xh/xl, agg1 only
    // writes rows < NN, and gemm1 no longer reads them) — but agg1 overwrote real
    // rows only; pads still zero from the memset above.

    // ---- layer 2: zbf = bf16(h1@W2) via MFMA; out = (agg+self)*inv + b2 ----
    gemm2m_kernel<<<NNP / 64, 256, 0, stream>>>(h1h, h1l, w2th, w2tl, zbf);
    agg2_kernel<<<NN / 8, 256, 0, stream>>>(zbf, rowptr, col, inv, b2, out, NN);
}